// Round 4
// baseline (197.921 us; speedup 1.0000x reference)
//
#include <hip/hip_runtime.h>
#include <math.h>

// SquaredGaussianMixture: N=2M points, D=4, K=8, scalar f32 output.
//
// Round-4 restructure: lane = (point-slot p = lane>>3) x (cluster k = lane&7).
// Each lane holds ONLY its cluster's 15 coefficients (lane-varying VGPRs),
// killing the 120-wave-uniform-coefficient register-pressure problem that
// caused spill/reload stalls in rounds 1-3 (VALUBusy 16-25%).
// Density via scaled Cholesky: d = exp2(c - ||G''x - t||^2), G'' = sqrt(ln2e/2)*inv(chol(S)).
// Pair products via xor-shuffle: acc[m] += d * shfl_xor(d, m); summing
// (k, m) over lanes covers every ORDERED pair (k, k^m) exactly once, so the
// final sum is sum_{k,m} W[k][k^m] * acc[k][m] with no doubling factors.

#define NSLOT 32  // contention-spreading slots per accumulator

struct WsLayout {
  double P[64 * NSLOT];  // partial sums, [k*8+m][slot]
  double Wfull[64];      // softmax weights, full 8x8
  double logz;
  unsigned int ctr;      // blocks-done counter
  unsigned int pad_;
  float g[10 * 8];       // lower-tri G'' coeffs, layout [coef][cluster]
  float tn[4 * 8];       // -G''*mu bias, layout [row][cluster]
  float cc[8];           // log2(coef_k)
};

__device__ inline void chol4(const double S[4][4], double G[4][4]) {
  #pragma unroll
  for (int i = 0; i < 4; ++i) {
    #pragma unroll
    for (int j = 0; j < 4; ++j) {
      if (j > i) { G[i][j] = 0.0; continue; }
      double s = S[i][j];
      #pragma unroll
      for (int m = 0; m < 4; ++m) if (m < j) s -= G[i][m] * G[j][m];
      if (i == j) G[i][j] = sqrt(s);
      else        G[i][j] = s / G[j][j];
    }
  }
}

__global__ void prep_kernel(const float* __restrict__ means,
                            const float* __restrict__ chols,
                            const float* __restrict__ weights,
                            WsLayout* ws) {
  __shared__ double sig[8][4][4];
  const double LOG2E = 1.4426950408889634074;
  const double LN2PI = 1.8378770664093454836;
  const int t = threadIdx.x;  // 0..63, one wave

  if (t < 8) {
    const int k = t;
    double L[4][4], S[4][4];
    #pragma unroll
    for (int i = 0; i < 4; ++i)
      #pragma unroll
      for (int j = 0; j < 4; ++j)
        L[i][j] = (j <= i) ? (double)chols[k * 16 + i * 4 + j] : 0.0;
    #pragma unroll
    for (int i = 0; i < 4; ++i)
      #pragma unroll
      for (int j = 0; j < 4; ++j) {
        double s = (i == j) ? 1.0 : 0.0;
        #pragma unroll
        for (int m = 0; m < 4; ++m) s += L[i][m] * L[j][m];
        S[i][j] = s;
        sig[k][i][j] = s;
      }
    double G[4][4];
    chol4(S, G);
    const double logdet =
        2.0 * (log(G[0][0]) + log(G[1][1]) + log(G[2][2]) + log(G[3][3]));
    // invert lower-triangular G
    double Gi[4][4];
    #pragma unroll
    for (int j = 0; j < 4; ++j) {
      #pragma unroll
      for (int i = 0; i < 4; ++i) {
        if (i < j) { Gi[i][j] = 0.0; continue; }
        double s = (i == j) ? 1.0 : 0.0;
        #pragma unroll
        for (int m = 0; m < 4; ++m)
          if (m >= j && m < i) s -= G[i][m] * Gi[m][j];
        Gi[i][j] = s / G[i][i];
      }
    }
    // scale: a = log2(coef) - ||G''(x-mu)||^2 with G'' = sqrt(0.5*log2e)*Gi
    const double sc = sqrt(0.5 * LOG2E);
    double mu[4];
    #pragma unroll
    for (int i = 0; i < 4; ++i) mu[i] = (double)means[k * 4 + i];
    int idx = 0;
    #pragma unroll
    for (int i = 0; i < 4; ++i) {
      double ti = 0.0;
      #pragma unroll
      for (int j = 0; j < 4; ++j) {
        const double gij = sc * Gi[i][j];
        if (j <= i) ws->g[(idx++) * 8 + k] = (float)gij;
        ti += gij * mu[j];
      }
      ws->tn[i * 8 + k] = (float)(-ti);
    }
    const double logcoef = -0.5 * (4.0 * LN2PI + logdet);  // ln
    ws->cc[k] = (float)(LOG2E * logcoef);
  }
  __syncthreads();

  // pairwise part: one thread per (i,j) of 8x8
  const int i = t >> 3, j = t & 7;
  const double wij = (double)weights[i] * (double)weights[j];
  double m = wij;
  #pragma unroll
  for (int o = 32; o > 0; o >>= 1) {
    double x = __shfl_xor(m, o, 64);
    m = fmax(m, x);
  }
  const double e = exp(wij - m);
  double ssum = e;
  #pragma unroll
  for (int o = 32; o > 0; o >>= 1) ssum += __shfl_xor(ssum, o, 64);
  const double Wij = e / ssum;
  ws->Wfull[t] = Wij;

  double SS[4][4];
  #pragma unroll
  for (int a = 0; a < 4; ++a)
    #pragma unroll
    for (int b = 0; b < 4; ++b) SS[a][b] = sig[i][a][b] + sig[j][a][b];
  double G2[4][4];
  chol4(SS, G2);
  const double logdetS =
      2.0 * (log(G2[0][0]) + log(G2[1][1]) + log(G2[2][2]) + log(G2[3][3]));
  double bvec[4], y[4];
  #pragma unroll
  for (int a = 0; a < 4; ++a)
    bvec[a] = (double)means[i * 4 + a] - (double)means[j * 4 + a];
  #pragma unroll
  for (int a = 0; a < 4; ++a) {
    double s = bvec[a];
    #pragma unroll
    for (int mm = 0; mm < 4; ++mm) if (mm < a) s -= G2[a][mm] * y[mm];
    y[a] = s / G2[a][a];
  }
  const double md = y[0]*y[0] + y[1]*y[1] + y[2]*y[2] + y[3]*y[3];
  double zterm = Wij * exp(-0.5 * md - 0.5 * (4.0 * LN2PI + logdetS));
  #pragma unroll
  for (int o = 32; o > 0; o >>= 1) zterm += __shfl_xor(zterm, o, 64);
  if (t == 0) { ws->logz = log(zterm); ws->ctr = 0u; }

  // zero the P accumulator slots (ws is poisoned 0xAA before every call)
  for (int u = t; u < 64 * NSLOT; u += 64) ws->P[u] = 0.0;
}

__global__ __launch_bounds__(256) void point_kernel(
    const float4* __restrict__ X, const WsLayout* __restrict__ wsc,
    double* __restrict__ P, unsigned int* ctr, float* __restrict__ out,
    int n) {
  const int lane = threadIdx.x & 63;
  const int wid = threadIdx.x >> 6;
  const int k = lane & 7;       // cluster
  const int pg = lane >> 3;     // point slot within batch (0..7)

  // per-lane cluster coefficients: 15 VGPRs, no uniform-copy pressure
  float g0, g1, g2, g3, g4, g5, g6, g7, g8, g9, t0, t1, t2, t3, ck;
  g0 = wsc->g[0 * 8 + k]; g1 = wsc->g[1 * 8 + k]; g2 = wsc->g[2 * 8 + k];
  g3 = wsc->g[3 * 8 + k]; g4 = wsc->g[4 * 8 + k]; g5 = wsc->g[5 * 8 + k];
  g6 = wsc->g[6 * 8 + k]; g7 = wsc->g[7 * 8 + k]; g8 = wsc->g[8 * 8 + k];
  g9 = wsc->g[9 * 8 + k];
  t0 = wsc->tn[0 * 8 + k]; t1 = wsc->tn[1 * 8 + k];
  t2 = wsc->tn[2 * 8 + k]; t3 = wsc->tn[3 * 8 + k];
  ck = wsc->cc[k];

  float acc[8];
  #pragma unroll
  for (int m = 0; m < 8; ++m) acc[m] = 0.0f;

  const int nb = n >> 3;                       // batches of 8 points (n%8==0)
  const int Wt = gridDim.x * (blockDim.x >> 6);  // total waves
  const int w = blockIdx.x * (blockDim.x >> 6) + wid;

  int b = w;
  for (; b + 3 * Wt < nb; b += 4 * Wt) {
    float4 v[4];
    #pragma unroll
    for (int j = 0; j < 4; ++j) v[j] = X[(b + j * Wt) * 8 + pg];
    #pragma unroll
    for (int j = 0; j < 4; ++j) {
      const float4 vv = v[j];
      const float y0 = fmaf(g0, vv.x, t0);
      const float y1 = fmaf(g2, vv.y, fmaf(g1, vv.x, t1));
      const float y2 = fmaf(g5, vv.z, fmaf(g4, vv.y, fmaf(g3, vv.x, t2)));
      const float y3 =
          fmaf(g9, vv.w, fmaf(g8, vv.z, fmaf(g7, vv.y, fmaf(g6, vv.x, t3))));
      float q = y0 * y0;
      q = fmaf(y1, y1, q);
      q = fmaf(y2, y2, q);
      q = fmaf(y3, y3, q);
      const float d = __builtin_amdgcn_exp2f(ck - q);
      acc[0] = fmaf(d, d, acc[0]);
      #pragma unroll
      for (int m = 1; m < 8; ++m)
        acc[m] = fmaf(d, __shfl_xor(d, m, 64), acc[m]);
    }
  }
  for (; b < nb; b += Wt) {
    const float4 vv = X[b * 8 + pg];
    const float y0 = fmaf(g0, vv.x, t0);
    const float y1 = fmaf(g2, vv.y, fmaf(g1, vv.x, t1));
    const float y2 = fmaf(g5, vv.z, fmaf(g4, vv.y, fmaf(g3, vv.x, t2)));
    const float y3 =
        fmaf(g9, vv.w, fmaf(g8, vv.z, fmaf(g7, vv.y, fmaf(g6, vv.x, t3))));
    float q = y0 * y0;
    q = fmaf(y1, y1, q);
    q = fmaf(y2, y2, q);
    q = fmaf(y3, y3, q);
    const float d = __builtin_amdgcn_exp2f(ck - q);
    acc[0] = fmaf(d, d, acc[0]);
    #pragma unroll
    for (int m = 1; m < 8; ++m)
      acc[m] = fmaf(d, __shfl_xor(d, m, 64), acc[m]);
  }

  // sum over the 8 point-slots (xor over lane bits 3,4,5)
  #pragma unroll
  for (int m = 0; m < 8; ++m) {
    acc[m] += __shfl_xor(acc[m], 8, 64);
    acc[m] += __shfl_xor(acc[m], 16, 64);
    acc[m] += __shfl_xor(acc[m], 32, 64);
  }
  // lanes 0..7 hold completed acc[k=lane][m] for this wave
  __shared__ double lred[4][64];
  if (lane < 8) {
    #pragma unroll
    for (int m = 0; m < 8; ++m) lred[wid][lane * 8 + m] = (double)acc[m];
  }
  __syncthreads();
  if (threadIdx.x < 64) {
    const double s = lred[0][threadIdx.x] + lred[1][threadIdx.x] +
                     lred[2][threadIdx.x] + lred[3][threadIdx.x];
    unsafeAtomicAdd(&P[threadIdx.x * NSLOT + (blockIdx.x & (NSLOT - 1))], s);
  }
  __syncthreads();

  // last block to finish performs the final reduction
  __shared__ int amLast;
  if (threadIdx.x == 0) {
    __threadfence();
    const unsigned int old = atomicAdd(ctr, 1u);
    amLast = (old == gridDim.x - 1u);
    __threadfence();
  }
  __syncthreads();
  if (amLast) {
    double val = 0.0;
    for (int i = (int)threadIdx.x; i < 64 * NSLOT; i += 256) {
      const int km = i / NSLOT;
      const int kk = km >> 3, mm = km & 7;
      const double pv = unsafeAtomicAdd(&P[i], 0.0);  // atomic read
      val += wsc->Wfull[kk * 8 + (kk ^ mm)] * pv;
    }
    #pragma unroll
    for (int o = 32; o > 0; o >>= 1) val += __shfl_xor(val, o, 64);
    __shared__ double fin[4];
    if (lane == 0) fin[wid] = val;
    __syncthreads();
    if (threadIdx.x == 0) {
      const double tot = fin[0] + fin[1] + fin[2] + fin[3];
      out[0] = (float)(-(log(tot) - wsc->logz) / (double)n);
    }
  }
}

extern "C" void kernel_launch(void* const* d_in, const int* in_sizes, int n_in,
                              void* d_out, int out_size, void* d_ws, size_t ws_size,
                              hipStream_t stream) {
  const float* X       = (const float*)d_in[0];
  const float* means   = (const float*)d_in[1];
  const float* chols   = (const float*)d_in[2];
  const float* weights = (const float*)d_in[3];
  const int npoints = in_sizes[0] / 4;  // 2,000,000 (divisible by 8)

  WsLayout* ws = (WsLayout*)d_ws;
  prep_kernel<<<1, 64, 0, stream>>>(means, chols, weights, ws);
  point_kernel<<<2048, 256, 0, stream>>>((const float4*)X, ws, ws->P, &ws->ctr,
                                         (float*)d_out, npoints);
}

// Round 5
// 131.184 us; speedup vs baseline: 1.5087x; 1.5087x over previous
//
#include <hip/hip_runtime.h>
#include <math.h>

// SquaredGaussianMixture: N=2M points, D=4, K=8, scalar f32 output.
//
// Round-5: single-accumulator form. Per point:
//   d_k = exp2(cc_k - ||G''_k x + t_k||^2)   (8x14 fma + 8 exp2)
//   s   = sum_{i<=j} W2_ij d_i d_j           (44 fma, W2 = softmax wt, offdiag x2)
//   sacc += s                                 (ONE accumulator -> no spills)
// Lessons: R1/R2 spilled 36 accs to scratch (VGPR_Count=36 proved it);
// R4's per-point shuffles stalled on the LDS pipe. Both eliminated here.
// 81 coefficients pinned to VGPRs via asm("+v") so the rest fit the SGPR file.

struct WsLayout {
  double tot[512];   // 64 slots at stride 8 doubles (64B) for atomic spreading
  double logz;
  unsigned int ctr;
  unsigned int pad_;
  float par[160];    // [k*15+0..9]=G'' tri, [+10..13]=t, [+14]=cc, [120+u]=W2
};

__device__ inline void chol4(const double S[4][4], double G[4][4]) {
  #pragma unroll
  for (int i = 0; i < 4; ++i) {
    #pragma unroll
    for (int j = 0; j < 4; ++j) {
      if (j > i) { G[i][j] = 0.0; continue; }
      double s = S[i][j];
      #pragma unroll
      for (int m = 0; m < 4; ++m) if (m < j) s -= G[i][m] * G[j][m];
      if (i == j) G[i][j] = sqrt(s);
      else        G[i][j] = s / G[j][j];
    }
  }
}

__global__ void prep_kernel(const float* __restrict__ means,
                            const float* __restrict__ chols,
                            const float* __restrict__ weights,
                            WsLayout* ws) {
  __shared__ double sig[8][4][4];
  const double LOG2E = 1.4426950408889634074;
  const double LN2PI = 1.8378770664093454836;
  const int t = threadIdx.x;  // 0..63, one wave

  if (t < 8) {
    const int k = t;
    double L[4][4], S[4][4];
    #pragma unroll
    for (int i = 0; i < 4; ++i)
      #pragma unroll
      for (int j = 0; j < 4; ++j)
        L[i][j] = (j <= i) ? (double)chols[k * 16 + i * 4 + j] : 0.0;
    #pragma unroll
    for (int i = 0; i < 4; ++i)
      #pragma unroll
      for (int j = 0; j < 4; ++j) {
        double s = (i == j) ? 1.0 : 0.0;
        #pragma unroll
        for (int m = 0; m < 4; ++m) s += L[i][m] * L[j][m];
        S[i][j] = s;
        sig[k][i][j] = s;
      }
    double G[4][4];
    chol4(S, G);
    const double logdet =
        2.0 * (log(G[0][0]) + log(G[1][1]) + log(G[2][2]) + log(G[3][3]));
    // invert lower-triangular G
    double Gi[4][4];
    #pragma unroll
    for (int j = 0; j < 4; ++j) {
      #pragma unroll
      for (int i = 0; i < 4; ++i) {
        if (i < j) { Gi[i][j] = 0.0; continue; }
        double s = (i == j) ? 1.0 : 0.0;
        #pragma unroll
        for (int m = 0; m < 4; ++m)
          if (m >= j && m < i) s -= G[i][m] * Gi[m][j];
        Gi[i][j] = s / G[i][i];
      }
    }
    // d = exp2(cc - ||G''(x) + t||^2), G'' = sqrt(0.5*log2e) * Gi, t = -G''*mu
    const double sc = sqrt(0.5 * LOG2E);
    double mu[4];
    #pragma unroll
    for (int i = 0; i < 4; ++i) mu[i] = (double)means[k * 4 + i];
    int idx = 0;
    #pragma unroll
    for (int i = 0; i < 4; ++i) {
      double ti = 0.0;
      #pragma unroll
      for (int j = 0; j < 4; ++j) {
        const double gij = sc * Gi[i][j];
        if (j <= i) ws->par[k * 15 + (idx++)] = (float)gij;
        ti += gij * mu[j];
      }
      ws->par[k * 15 + 10 + i] = (float)(-ti);
    }
    const double logcoef = -0.5 * (4.0 * LN2PI + logdet);  // ln of coef
    ws->par[k * 15 + 14] = (float)(LOG2E * logcoef);
  }
  __syncthreads();

  // pairwise part: one thread per (i,j) of 8x8
  const int i = t >> 3, j = t & 7;
  const double wij = (double)weights[i] * (double)weights[j];
  double m = wij;
  #pragma unroll
  for (int o = 32; o > 0; o >>= 1) {
    double x = __shfl_xor(m, o, 64);
    m = fmax(m, x);
  }
  const double e = exp(wij - m);
  double ssum = e;
  #pragma unroll
  for (int o = 32; o > 0; o >>= 1) ssum += __shfl_xor(ssum, o, 64);
  const double Wij = e / ssum;

  // packed upper-tri softmax weight, off-diag doubled
  if (i <= j) {
    const int u = 8 * i - (i * (i - 1)) / 2 + (j - i);
    ws->par[120 + u] = (float)(Wij * ((i == j) ? 1.0 : 2.0));
  }

  double SS[4][4];
  #pragma unroll
  for (int a = 0; a < 4; ++a)
    #pragma unroll
    for (int b = 0; b < 4; ++b) SS[a][b] = sig[i][a][b] + sig[j][a][b];
  double G2[4][4];
  chol4(SS, G2);
  const double logdetS =
      2.0 * (log(G2[0][0]) + log(G2[1][1]) + log(G2[2][2]) + log(G2[3][3]));
  double bvec[4], y[4];
  #pragma unroll
  for (int a = 0; a < 4; ++a)
    bvec[a] = (double)means[i * 4 + a] - (double)means[j * 4 + a];
  #pragma unroll
  for (int a = 0; a < 4; ++a) {
    double s = bvec[a];
    #pragma unroll
    for (int mm = 0; mm < 4; ++mm) if (mm < a) s -= G2[a][mm] * y[mm];
    y[a] = s / G2[a][a];
  }
  const double md = y[0]*y[0] + y[1]*y[1] + y[2]*y[2] + y[3]*y[3];
  double zterm = Wij * exp(-0.5 * md - 0.5 * (4.0 * LN2PI + logdetS));
  #pragma unroll
  for (int o = 32; o > 0; o >>= 1) zterm += __shfl_xor(zterm, o, 64);
  if (t == 0) { ws->logz = log(zterm); ws->ctr = 0u; }

  // zero the atomic slots (ws is poisoned 0xAA before every call)
  for (int u = t; u < 512; u += 64) ws->tot[u] = 0.0;
}

// per-point density-pair sum; ~165 VALU, no cross-lane ops
__device__ inline float point_s(const float4 v, const float g[8][10],
                                const float tn[8][4], const float cc[8],
                                const float W2[36]) {
  float d[8];
  #pragma unroll
  for (int k = 0; k < 8; ++k) {
    const float y0 = fmaf(g[k][0], v.x, tn[k][0]);
    const float y1 = fmaf(g[k][2], v.y, fmaf(g[k][1], v.x, tn[k][1]));
    const float y2 =
        fmaf(g[k][5], v.z, fmaf(g[k][4], v.y, fmaf(g[k][3], v.x, tn[k][2])));
    const float y3 = fmaf(
        g[k][9], v.w,
        fmaf(g[k][8], v.z, fmaf(g[k][7], v.y, fmaf(g[k][6], v.x, tn[k][3]))));
    float a = cc[k];            // a = cc - sum y^2, negation via fma modifier
    a = fmaf(y0, -y0, a);
    a = fmaf(y1, -y1, a);
    a = fmaf(y2, -y2, a);
    a = fmaf(y3, -y3, a);
    d[k] = __builtin_amdgcn_exp2f(a);
  }
  float s = 0.0f;
  int u = 0;
  #pragma unroll
  for (int i = 0; i < 8; ++i) {
    float tt = W2[u++] * d[i];  // j == i term
    #pragma unroll
    for (int j = i + 1; j < 8; ++j) tt = fmaf(W2[u++], d[j], tt);
    s = fmaf(d[i], tt, s);
  }
  return s;
}

__global__ void point_kernel(const float4* __restrict__ X,
                             const WsLayout* __restrict__ wsc,
                             double* __restrict__ tot, unsigned int* ctr,
                             float* __restrict__ out, int n) {
  const int lane = threadIdx.x & 63;
  const int wid = threadIdx.x >> 6;
  const float* par = wsc->par;

  float g[8][10], tn[8][4], cc[8], W2[36];
  #pragma unroll
  for (int k = 0; k < 8; ++k) {
    #pragma unroll
    for (int u = 0; u < 10; ++u) g[k][u] = par[k * 15 + u];
    #pragma unroll
    for (int u = 0; u < 4; ++u) tn[k][u] = par[k * 15 + 10 + u];
    cc[k] = par[k * 15 + 14];
  }
  #pragma unroll
  for (int u = 0; u < 36; ++u) W2[u] = par[120 + u];

  // Pin clusters 5..7 (45) + W2 (36) = 81 coefficients into VGPRs so the
  // remaining 75 fit the ~102-SGPR file without in-loop scalar reloads.
  #pragma unroll
  for (int k = 5; k < 8; ++k) {
    #pragma unroll
    for (int u = 0; u < 10; ++u) asm volatile("" : "+v"(g[k][u]));
    #pragma unroll
    for (int u = 0; u < 4; ++u) asm volatile("" : "+v"(tn[k][u]));
    asm volatile("" : "+v"(cc[k]));
  }
  #pragma unroll
  for (int u = 0; u < 36; ++u) asm volatile("" : "+v"(W2[u]));

  const int S = gridDim.x * blockDim.x;
  float sacc = 0.0f;
  int i = blockIdx.x * blockDim.x + threadIdx.x;
  for (; i + S < n; i += 2 * S) {  // unroll-2: two independent loads in flight
    const float4 va = X[i];
    const float4 vb = X[i + S];
    sacc += point_s(va, g, tn, cc, W2);
    sacc += point_s(vb, g, tn, cc, W2);
  }
  for (; i < n; i += S) sacc += point_s(X[i], g, tn, cc, W2);

  // block reduce: f64 wave butterfly (once) -> LDS -> one atomic per block
  double bs = (double)sacc;
  #pragma unroll
  for (int o = 32; o > 0; o >>= 1) bs += __shfl_xor(bs, o, 64);
  __shared__ double lred[4];
  if (lane == 0) lred[wid] = bs;
  __syncthreads();
  if (threadIdx.x == 0) {
    const double v = lred[0] + lred[1] + lred[2] + lred[3];
    unsafeAtomicAdd(&tot[(blockIdx.x & 63) * 8], v);  // 64 slots, 64B apart
  }
  __syncthreads();

  __shared__ int amLast;
  if (threadIdx.x == 0) {
    __threadfence();
    const unsigned int old = atomicAdd(ctr, 1u);
    amLast = (old == gridDim.x - 1u);
    __threadfence();
  }
  __syncthreads();
  if (amLast && threadIdx.x < 64) {
    // atomic reads — same coherence path as the slot writes
    double val = unsafeAtomicAdd(&tot[threadIdx.x * 8], 0.0);
    #pragma unroll
    for (int o = 32; o > 0; o >>= 1) val += __shfl_xor(val, o, 64);
    if (threadIdx.x == 0)
      out[0] = (float)(-(log(val) - wsc->logz) / (double)n);
  }
}

extern "C" void kernel_launch(void* const* d_in, const int* in_sizes, int n_in,
                              void* d_out, int out_size, void* d_ws, size_t ws_size,
                              hipStream_t stream) {
  const float* X       = (const float*)d_in[0];
  const float* means   = (const float*)d_in[1];
  const float* chols   = (const float*)d_in[2];
  const float* weights = (const float*)d_in[3];
  const int npoints = in_sizes[0] / 4;  // 2,000,000

  WsLayout* ws = (WsLayout*)d_ws;
  prep_kernel<<<1, 64, 0, stream>>>(means, chols, weights, ws);
  point_kernel<<<1024, 256, 0, stream>>>((const float4*)X, ws, ws->tot,
                                         &ws->ctr, (float*)d_out, npoints);
}